// Round 7
// baseline (144.758 us; speedup 1.0000x reference)
//
#include <hip/hip_runtime.h>

#define D 128
#define TM 32   // rows per block; 2 waves x 16 rows -> 1563 blocks, 16 waves/CU resident

typedef __attribute__((ext_vector_type(8))) short short8v;
typedef __attribute__((ext_vector_type(4))) float float4v;

// Native bf16 convert (RNE) - compiler emits v_cvt_pk_bf16_f32.
__device__ __forceinline__ unsigned short f2bf(float f) {
    __bf16 h = (__bf16)f;
    return __builtin_bit_cast(unsigned short, h);
}
__device__ __forceinline__ float bflo(int u) {
    return __uint_as_float(((unsigned int)u) << 16);
}
__device__ __forceinline__ float bfhi(int u) {
    return __uint_as_float(((unsigned int)u) & 0xFFFF0000u);
}

// Convert 3 weight matrices (each [128][128] fp32, row-major [n][k]) into
// bf16 MFMA B-fragment order:
// dst[((t*4+ks)*64 + lane)*8 + j] = W[t*16+(lane&15)][ks*32+(lane>>4)*8+j]
__global__ __launch_bounds__(256) void wconv(
    const float* __restrict__ w1, const float* __restrict__ w2,
    const float* __restrict__ wb, unsigned short* __restrict__ dst)
{
    int tid = blockIdx.x * 256 + threadIdx.x;   // 0..6143
    int w = tid >> 11;          // which weight
    int r = tid & 2047;         // (t*4+ks)*64 + lane
    int l = r & 63;
    int tk = r >> 6;            // t*4+ks
    int t = tk >> 2, ks = tk & 3;
    int n = t * 16 + (l & 15);
    int k = ks * 32 + (l >> 4) * 8;
    const float* src = (w == 0) ? w1 : (w == 1) ? w2 : wb;
    const float* p = src + n * D + k;
    float4 a = *(const float4*)p;
    float4 b = *(const float4*)(p + 4);
    union { int4 i4; unsigned short u[8]; } pk;
    pk.u[0] = f2bf(a.x); pk.u[1] = f2bf(a.y); pk.u[2] = f2bf(a.z); pk.u[3] = f2bf(a.w);
    pk.u[4] = f2bf(b.x); pk.u[5] = f2bf(b.y); pk.u[6] = f2bf(b.z); pk.u[7] = f2bf(b.w);
    *(int4*)(dst + (size_t)tid * 8) = pk.i4;
}

// Fused node kernel v7: identical per-wave chain to the 140.5us v3 kernel,
// but TM=32 / 128-thread blocks so residency rises 12 -> 16 waves/CU:
//   - v3: 136 VGPR -> 3 waves/SIMD cap; grid 3128 waves ~ 12.2/CU available.
//   - v7: __launch_bounds__(128,4) caps VGPR at 128 -> 4 waves/SIMD;
//     grid 3126 waves ~ 24/CU available, 16/CU resident; LDS 17.4KB (9 blk/CU).
// BARRIER-FREE: each wave owns rows [wave*16, wave*16+16) of both buffers.
//   sa: LN(z) -> GEMM1/2 A-reads -> h2 (epi2) -> GEMM3 A-reads
//   sh: h1 (epi1) -> copyout T1  -> GEMM3 out -> copyout T2
__global__ __launch_bounds__(128, 4) void node_kernel(
    const float* __restrict__ z,
    const unsigned short* __restrict__ wfrag,
    const float* __restrict__ lin1_b, const float* __restrict__ lin2_b,
    const float* __restrict__ norm_w, const float* __restrict__ norm_b,
    unsigned short* __restrict__ T1, unsigned short* __restrict__ T2,
    int N)
{
    __shared__ unsigned short sa[TM][136];
    __shared__ unsigned short sh[TM][136];

    const int tid   = threadIdx.x;
    const int lane  = tid & 63;
    const int wave  = tid >> 6;     // 0..1
    const int n0    = blockIdx.x * TM;
    const int cg    = lane & 15;
    const int q     = lane >> 4;
    const int rbase = wave * 16;

    // ---- phase 1: LN(z) -> sa (own 16 rows) ----
    {
        const int c = cg * 8;
        float4 nw0 = *(const float4*)(norm_w + c);
        float4 nw1 = *(const float4*)(norm_w + c + 4);
        float4 nb0 = *(const float4*)(norm_b + c);
        float4 nb1 = *(const float4*)(norm_b + c + 4);
        #pragma unroll
        for (int it = 0; it < 4; ++it) {
            int rr = rbase + it * 4 + q;
            int n  = n0 + rr;
            int nc = (n < N) ? n : (N - 1);
            const float* zp = z + (size_t)nc * D + c;
            float4 v0 = *(const float4*)zp;
            float4 v1 = *(const float4*)(zp + 4);
            float s  = v0.x + v0.y + v0.z + v0.w + v1.x + v1.y + v1.z + v1.w;
            float qq = v0.x*v0.x + v0.y*v0.y + v0.z*v0.z + v0.w*v0.w
                     + v1.x*v1.x + v1.y*v1.y + v1.z*v1.z + v1.w*v1.w;
            #pragma unroll
            for (int m = 1; m <= 8; m <<= 1) {
                s  += __shfl_xor(s, m, 64);
                qq += __shfl_xor(qq, m, 64);
            }
            float mu  = s * (1.0f / D);
            float var = qq * (1.0f / D) - mu * mu;
            float rs  = rsqrtf(var + 1e-5f);
            union { int4 i4; unsigned short u[8]; } pk;
            pk.u[0] = f2bf((v0.x - mu) * rs * nw0.x + nb0.x);
            pk.u[1] = f2bf((v0.y - mu) * rs * nw0.y + nb0.y);
            pk.u[2] = f2bf((v0.z - mu) * rs * nw0.z + nb0.z);
            pk.u[3] = f2bf((v0.w - mu) * rs * nw0.w + nb0.w);
            pk.u[4] = f2bf((v1.x - mu) * rs * nw1.x + nb1.x);
            pk.u[5] = f2bf((v1.y - mu) * rs * nw1.y + nb1.y);
            pk.u[6] = f2bf((v1.z - mu) * rs * nw1.z + nb1.z);
            pk.u[7] = f2bf((v1.w - mu) * rs * nw1.w + nb1.w);
            *(int4*)&sa[rr][c] = pk.i4;
        }
    }

    // ---- GEMM1 + GEMM2 fused (dual accumulators) ----
    float4v acc1[8], acc2[8];
    #pragma unroll
    for (int t = 0; t < 8; ++t) { acc1[t] = (float4v)(0.0f); acc2[t] = (float4v)(0.0f); }
    #pragma unroll
    for (int ks = 0; ks < 4; ++ks) {
        short8v a = *(const short8v*)&sa[rbase + cg][ks * 32 + q * 8];
        const short8v* wp = (const short8v*)wfrag + ks * 64 + lane;
        #pragma unroll
        for (int t = 0; t < 8; ++t) {
            acc1[t] = __builtin_amdgcn_mfma_f32_16x16x32_bf16(a, wp[t * 256],        acc1[t], 0, 0, 0);
            acc2[t] = __builtin_amdgcn_mfma_f32_16x16x32_bf16(a, wp[t * 256 + 2048], acc2[t], 0, 0, 0);
        }
    }

    // epilogue LN params preloaded once (col = t*16+cg), shared by both epilogues
    float nwv[8], nbv[8];
    #pragma unroll
    for (int t = 0; t < 8; ++t) {
        nwv[t] = norm_w[t * 16 + cg];
        nbv[t] = norm_b[t * 16 + cg];
    }

    // bias+relu+LN epilogue (C-layout: col=t*16+cg, row=rbase+q*4+i) -> dst
    auto epilogue = [&](float4v* acc, const float* lb, unsigned short (*dst)[136]) {
        float s[4] = {0, 0, 0, 0}, qs[4] = {0, 0, 0, 0};
        #pragma unroll
        for (int t = 0; t < 8; ++t) {
            float b = lb[t * 16 + cg];
            #pragma unroll
            for (int i = 0; i < 4; ++i) {
                float v = fmaxf(acc[t][i] + b, 0.0f);
                acc[t][i] = v;
                s[i] += v; qs[i] += v * v;
            }
        }
        #pragma unroll
        for (int i = 0; i < 4; ++i) {
            #pragma unroll
            for (int m = 1; m <= 8; m <<= 1) {
                s[i]  += __shfl_xor(s[i], m, 64);
                qs[i] += __shfl_xor(qs[i], m, 64);
            }
            float mu  = s[i] * (1.0f / D);
            float var = qs[i] * (1.0f / D) - mu * mu;
            s[i] = mu; qs[i] = rsqrtf(var + 1e-5f);
        }
        #pragma unroll
        for (int t = 0; t < 8; ++t) {
            #pragma unroll
            for (int i = 0; i < 4; ++i)
                dst[rbase + q * 4 + i][t * 16 + cg] = f2bf((acc[t][i] - s[i]) * qs[i] * nwv[t] + nbv[t]);
        }
    };

    // coalesced LDS -> global bf16 copy of own 16 rows
    auto copyout = [&](const unsigned short (*S)[136], unsigned short* dst) {
        int r = rbase + (lane >> 2);
        int n = n0 + r;
        if (n < N) {
            #pragma unroll
            for (int j = 0; j < 4; ++j) {
                int c = (lane & 3) * 8 + j * 32;
                *(int4*)(dst + (size_t)n * D + c) = *(const int4*)&S[r][c];
            }
        }
    };

    epilogue(acc1, lin1_b, sh);   // h1 -> sh
    epilogue(acc2, lin2_b, sa);   // h2 -> sa (GEMM1/2 A-reads of sa are done)
    copyout(sh, T1);

    // ---- GEMM3: T2 = H2 @ Wb^T  (A from sa, result staged through sh) ----
    #pragma unroll
    for (int t = 0; t < 8; ++t) acc1[t] = (float4v)(0.0f);
    #pragma unroll
    for (int ks = 0; ks < 4; ++ks) {
        short8v a = *(const short8v*)&sa[rbase + cg][ks * 32 + q * 8];
        const short8v* wp = (const short8v*)wfrag + 4096 + ks * 64 + lane;
        #pragma unroll
        for (int t = 0; t < 8; ++t)
            acc1[t] = __builtin_amdgcn_mfma_f32_16x16x32_bf16(a, wp[t * 256], acc1[t], 0, 0, 0);
    }
    #pragma unroll
    for (int t = 0; t < 8; ++t)
        #pragma unroll
        for (int i = 0; i < 4; ++i)
            sh[rbase + q * 4 + i][t * 16 + cg] = f2bf(acc1[t][i]);
    copyout(sh, T2);
}

// score[e] = dot(T1[a0], T2[a1]) + bb
// 32 arcs/wave (two 16-arc groups), 4 lanes/arc; 16 independent 16B gathers
// in flight per lane.
__global__ __launch_bounds__(256) void arc_kernel(
    const int* __restrict__ arcs,
    const unsigned short* __restrict__ T1,
    const unsigned short* __restrict__ T2,
    const float* __restrict__ bil_b,
    float* __restrict__ out, int E)
{
    const int tid  = threadIdx.x;
    const int lane = tid & 63;
    long long gw = ((long long)blockIdx.x * 256 + tid) >> 6;   // global wave id
    long long e0 = gw * 32;        // 32 arcs per wave
    int aidx = lane >> 2;          // arc-in-group (0..15)
    int s    = lane & 3;           // lane within arc

    // 64 distinct index ints per wave: arc k's (a0,a1) at lanes (2k, 2k+1)
    long long ii = e0 * 2 + lane;
    long long iimax = (long long)E * 2 - 1;
    int iv = arcs[ii <= iimax ? ii : iimax];
    int a0A = __shfl(iv, aidx * 2, 64);
    int a1A = __shfl(iv, aidx * 2 + 1, 64);
    int a0B = __shfl(iv, 32 + aidx * 2, 64);
    int a1B = __shfl(iv, 32 + aidx * 2 + 1, 64);

    const int4* PA = (const int4*)(T1 + (size_t)a0A * D);
    const int4* QA = (const int4*)(T2 + (size_t)a1A * D);
    const int4* PB = (const int4*)(T1 + (size_t)a0B * D);
    const int4* QB = (const int4*)(T2 + (size_t)a1B * D);

    // issue all 16 gathers up front
    int4 xA0 = PA[s];      int4 xA1 = PA[s + 4];
    int4 xA2 = PA[s + 8];  int4 xA3 = PA[s + 12];
    int4 yA0 = QA[s];      int4 yA1 = QA[s + 4];
    int4 yA2 = QA[s + 8];  int4 yA3 = QA[s + 12];
    int4 xB0 = PB[s];      int4 xB1 = PB[s + 4];
    int4 xB2 = PB[s + 8];  int4 xB3 = PB[s + 12];
    int4 yB0 = QB[s];      int4 yB1 = QB[s + 4];
    int4 yB2 = QB[s + 8];  int4 yB3 = QB[s + 12];

    auto dot16 = [](int4 x0, int4 x1, int4 x2, int4 x3,
                    int4 y0, int4 y1, int4 y2, int4 y3) -> float {
        float acc = 0.0f;
        acc += bflo(x0.x)*bflo(y0.x) + bfhi(x0.x)*bfhi(y0.x);
        acc += bflo(x0.y)*bflo(y0.y) + bfhi(x0.y)*bfhi(y0.y);
        acc += bflo(x0.z)*bflo(y0.z) + bfhi(x0.z)*bfhi(y0.z);
        acc += bflo(x0.w)*bflo(y0.w) + bfhi(x0.w)*bfhi(y0.w);
        acc += bflo(x1.x)*bflo(y1.x) + bfhi(x1.x)*bfhi(y1.x);
        acc += bflo(x1.y)*bflo(y1.y) + bfhi(x1.y)*bfhi(y1.y);
        acc += bflo(x1.z)*bflo(y1.z) + bfhi(x1.z)*bfhi(y1.z);
        acc += bflo(x1.w)*bflo(y1.w) + bfhi(x1.w)*bfhi(y1.w);
        acc += bflo(x2.x)*bflo(y2.x) + bfhi(x2.x)*bfhi(y2.x);
        acc += bflo(x2.y)*bflo(y2.y) + bfhi(x2.y)*bfhi(y2.y);
        acc += bflo(x2.z)*bflo(y2.z) + bfhi(x2.z)*bfhi(y2.z);
        acc += bflo(x2.w)*bflo(y2.w) + bfhi(x2.w)*bfhi(y2.w);
        acc += bflo(x3.x)*bflo(y3.x) + bfhi(x3.x)*bfhi(y3.x);
        acc += bflo(x3.y)*bflo(y3.y) + bfhi(x3.y)*bfhi(y3.y);
        acc += bflo(x3.z)*bflo(y3.z) + bfhi(x3.z)*bfhi(y3.z);
        acc += bflo(x3.w)*bflo(y3.w) + bfhi(x3.w)*bfhi(y3.w);
        return acc;
    };

    float accA = dot16(xA0, xA1, xA2, xA3, yA0, yA1, yA2, yA3);
    float accB = dot16(xB0, xB1, xB2, xB3, yB0, yB1, yB2, yB3);

    accA += __shfl_xor(accA, 1, 64);
    accA += __shfl_xor(accA, 2, 64);
    accB += __shfl_xor(accB, 1, 64);
    accB += __shfl_xor(accB, 2, 64);

    if (s == 0) {
        float bb = bil_b[0];
        long long eA = e0 + aidx;
        long long eB = e0 + 16 + aidx;
        if (eA < E) out[eA] = accA + bb;
        if (eB < E) out[eB] = accB + bb;
    }
}

extern "C" void kernel_launch(void* const* d_in, const int* in_sizes, int n_in,
                              void* d_out, int out_size, void* d_ws, size_t ws_size,
                              hipStream_t stream) {
    const float* z      = (const float*)d_in[0];
    const int*   arcs   = (const int*)d_in[1];
    const float* lin1_w = (const float*)d_in[2];
    const float* lin1_b = (const float*)d_in[3];
    const float* lin2_w = (const float*)d_in[4];
    const float* lin2_b = (const float*)d_in[5];
    const float* bil_w  = (const float*)d_in[6];
    const float* bil_b  = (const float*)d_in[7];
    const float* norm_w = (const float*)d_in[8];
    const float* norm_b = (const float*)d_in[9];
    float* out = (float*)d_out;

    const int N = in_sizes[0] / D;
    const int E = in_sizes[1] / 2;

    unsigned short* wfrag = (unsigned short*)d_ws;          // 3 * 16384 shorts
    unsigned short* T1 = wfrag + 3 * 16384;
    unsigned short* T2 = T1 + (size_t)N * D;

    wconv<<<24, 256, 0, stream>>>(lin1_w, lin2_w, bil_w, wfrag);

    node_kernel<<<(N + TM - 1) / TM, 128, 0, stream>>>(
        z, wfrag, lin1_b, lin2_b, norm_w, norm_b, T1, T2, N);

    long long waves = ((long long)E + 31) / 32;
    int blocks = (int)((waves + 3) / 4);
    arc_kernel<<<blocks, 256, 0, stream>>>(arcs, T1, T2, bil_b, out, E);
}

// Round 9
// 140.242 us; speedup vs baseline: 1.0322x; 1.0322x over previous
//
#include <hip/hip_runtime.h>

#define D 128
#define TM 64

typedef __attribute__((ext_vector_type(8))) short short8v;
typedef __attribute__((ext_vector_type(4))) float float4v;

__device__ __forceinline__ unsigned short f2bf(float f) {
    unsigned int u = __float_as_uint(f);
    u += 0x7FFFu + ((u >> 16) & 1u);   // round-to-nearest-even
    return (unsigned short)(u >> 16);
}
__device__ __forceinline__ float bflo(int u) {
    return __uint_as_float(((unsigned int)u) << 16);
}
__device__ __forceinline__ float bfhi(int u) {
    return __uint_as_float(((unsigned int)u) & 0xFFFF0000u);
}

// Convert 3 weight matrices (each [128][128] fp32, row-major [n][k]) into
// bf16 MFMA B-fragment order:
// dst[((t*4+ks)*64 + lane)*8 + j] = W[t*16+(lane&15)][ks*32+(lane>>4)*8+j]
__global__ __launch_bounds__(256) void wconv(
    const float* __restrict__ w1, const float* __restrict__ w2,
    const float* __restrict__ wb, unsigned short* __restrict__ dst)
{
    int tid = blockIdx.x * 256 + threadIdx.x;   // 0..6143
    int w = tid >> 11;          // which weight
    int r = tid & 2047;         // (t*4+ks)*64 + lane
    int l = r & 63;
    int tk = r >> 6;            // t*4+ks
    int t = tk >> 2, ks = tk & 3;
    int n = t * 16 + (l & 15);
    int k = ks * 32 + (l >> 4) * 8;
    const float* src = (w == 0) ? w1 : (w == 1) ? w2 : wb;
    const float* p = src + n * D + k;
    float4 a = *(const float4*)p;
    float4 b = *(const float4*)(p + 4);
    union { int4 i4; unsigned short u[8]; } pk;
    pk.u[0] = f2bf(a.x); pk.u[1] = f2bf(a.y); pk.u[2] = f2bf(a.z); pk.u[3] = f2bf(a.w);
    pk.u[4] = f2bf(b.x); pk.u[5] = f2bf(b.y); pk.u[6] = f2bf(b.z); pk.u[7] = f2bf(b.w);
    *(int4*)(dst + (size_t)tid * 8) = pk.i4;
}

// Fused node kernel (round-3 best config, unchanged): BARRIER-FREE, each wave
// owns rows [wave*16, wave*16+16) of both LDS buffers.
//   sa: LN(z) -> GEMM1/2 A-reads -> h2 (epi2) -> GEMM3 A-reads
//   sh: h1 (epi1) -> copyout T1  -> GEMM3 out -> copyout T2
// LDS 34.8 KB => 4 blocks/CU; 136 VGPR -> 12 waves/CU. Bracketed optimum:
// TM=128 (+10us), TM=32 (+4us), t-split (+4us), forced launch bounds (spills).
__global__ __launch_bounds__(256) void node_kernel(
    const float* __restrict__ z,
    const unsigned short* __restrict__ wfrag,
    const float* __restrict__ lin1_b, const float* __restrict__ lin2_b,
    const float* __restrict__ norm_w, const float* __restrict__ norm_b,
    unsigned short* __restrict__ T1, unsigned short* __restrict__ T2,
    int N)
{
    __shared__ unsigned short sa[TM][136];
    __shared__ unsigned short sh[TM][136];

    const int tid   = threadIdx.x;
    const int lane  = tid & 63;
    const int wave  = tid >> 6;
    const int n0    = blockIdx.x * TM;
    const int cg    = lane & 15;
    const int q     = lane >> 4;
    const int rbase = wave * 16;

    // ---- phase 1: LN(z) -> sa (own 16 rows) ----
    {
        const int c = cg * 8;
        float4 nw0 = *(const float4*)(norm_w + c);
        float4 nw1 = *(const float4*)(norm_w + c + 4);
        float4 nb0 = *(const float4*)(norm_b + c);
        float4 nb1 = *(const float4*)(norm_b + c + 4);
        #pragma unroll
        for (int it = 0; it < 4; ++it) {
            int rr = rbase + it * 4 + q;
            int n  = n0 + rr;
            int nc = (n < N) ? n : (N - 1);
            const float* zp = z + (size_t)nc * D + c;
            float4 v0 = *(const float4*)zp;
            float4 v1 = *(const float4*)(zp + 4);
            float s  = v0.x + v0.y + v0.z + v0.w + v1.x + v1.y + v1.z + v1.w;
            float qq = v0.x*v0.x + v0.y*v0.y + v0.z*v0.z + v0.w*v0.w
                     + v1.x*v1.x + v1.y*v1.y + v1.z*v1.z + v1.w*v1.w;
            #pragma unroll
            for (int m = 1; m <= 8; m <<= 1) {
                s  += __shfl_xor(s, m, 64);
                qq += __shfl_xor(qq, m, 64);
            }
            float mu  = s * (1.0f / D);
            float var = qq * (1.0f / D) - mu * mu;
            float rs  = rsqrtf(var + 1e-5f);
            union { int4 i4; unsigned short u[8]; } pk;
            pk.u[0] = f2bf((v0.x - mu) * rs * nw0.x + nb0.x);
            pk.u[1] = f2bf((v0.y - mu) * rs * nw0.y + nb0.y);
            pk.u[2] = f2bf((v0.z - mu) * rs * nw0.z + nb0.z);
            pk.u[3] = f2bf((v0.w - mu) * rs * nw0.w + nb0.w);
            pk.u[4] = f2bf((v1.x - mu) * rs * nw1.x + nb1.x);
            pk.u[5] = f2bf((v1.y - mu) * rs * nw1.y + nb1.y);
            pk.u[6] = f2bf((v1.z - mu) * rs * nw1.z + nb1.z);
            pk.u[7] = f2bf((v1.w - mu) * rs * nw1.w + nb1.w);
            *(int4*)&sa[rr][c] = pk.i4;
        }
    }

    // ---- GEMM1 + GEMM2 fused (dual accumulators) ----
    float4v acc1[8], acc2[8];
    #pragma unroll
    for (int t = 0; t < 8; ++t) { acc1[t] = (float4v)(0.0f); acc2[t] = (float4v)(0.0f); }
    #pragma unroll
    for (int ks = 0; ks < 4; ++ks) {
        short8v a = *(const short8v*)&sa[rbase + cg][ks * 32 + q * 8];
        const short8v* wp = (const short8v*)wfrag + ks * 64 + lane;
        #pragma unroll
        for (int t = 0; t < 8; ++t) {
            acc1[t] = __builtin_amdgcn_mfma_f32_16x16x32_bf16(a, wp[t * 256],        acc1[t], 0, 0, 0);
            acc2[t] = __builtin_amdgcn_mfma_f32_16x16x32_bf16(a, wp[t * 256 + 2048], acc2[t], 0, 0, 0);
        }
    }

    // epilogue LN params preloaded once (col = t*16+cg), shared by both epilogues
    float nwv[8], nbv[8];
    #pragma unroll
    for (int t = 0; t < 8; ++t) {
        nwv[t] = norm_w[t * 16 + cg];
        nbv[t] = norm_b[t * 16 + cg];
    }

    // bias+relu+LN epilogue (C-layout: col=t*16+cg, row=rbase+q*4+i) -> dst
    auto epilogue = [&](float4v* acc, const float* lb, unsigned short (*dst)[136]) {
        float s[4] = {0, 0, 0, 0}, qs[4] = {0, 0, 0, 0};
        #pragma unroll
        for (int t = 0; t < 8; ++t) {
            float b = lb[t * 16 + cg];
            #pragma unroll
            for (int i = 0; i < 4; ++i) {
                float v = fmaxf(acc[t][i] + b, 0.0f);
                acc[t][i] = v;
                s[i] += v; qs[i] += v * v;
            }
        }
        #pragma unroll
        for (int i = 0; i < 4; ++i) {
            #pragma unroll
            for (int m = 1; m <= 8; m <<= 1) {
                s[i]  += __shfl_xor(s[i], m, 64);
                qs[i] += __shfl_xor(qs[i], m, 64);
            }
            float mu  = s[i] * (1.0f / D);
            float var = qs[i] * (1.0f / D) - mu * mu;
            s[i] = mu; qs[i] = rsqrtf(var + 1e-5f);
        }
        #pragma unroll
        for (int t = 0; t < 8; ++t) {
            #pragma unroll
            for (int i = 0; i < 4; ++i)
                dst[rbase + q * 4 + i][t * 16 + cg] = f2bf((acc[t][i] - s[i]) * qs[i] * nwv[t] + nbv[t]);
        }
    };

    // coalesced LDS -> global bf16 copy of own 16 rows
    auto copyout = [&](const unsigned short (*S)[136], unsigned short* dst) {
        int r = rbase + (lane >> 2);
        int n = n0 + r;
        if (n < N) {
            #pragma unroll
            for (int j = 0; j < 4; ++j) {
                int c = (lane & 3) * 8 + j * 32;
                *(int4*)(dst + (size_t)n * D + c) = *(const int4*)&S[r][c];
            }
        }
    };

    epilogue(acc1, lin1_b, sh);   // h1 -> sh
    epilogue(acc2, lin2_b, sa);   // h2 -> sa (GEMM1/2 A-reads of sa are done)
    copyout(sh, T1);

    // ---- GEMM3: T2 = H2 @ Wb^T  (A from sa, result staged through sh) ----
    #pragma unroll
    for (int t = 0; t < 8; ++t) acc1[t] = (float4v)(0.0f);
    #pragma unroll
    for (int ks = 0; ks < 4; ++ks) {
        short8v a = *(const short8v*)&sa[rbase + cg][ks * 32 + q * 8];
        const short8v* wp = (const short8v*)wfrag + 4096 + ks * 64 + lane;
        #pragma unroll
        for (int t = 0; t < 8; ++t)
            acc1[t] = __builtin_amdgcn_mfma_f32_16x16x32_bf16(a, wp[t * 256], acc1[t], 0, 0, 0);
    }
    #pragma unroll
    for (int t = 0; t < 8; ++t)
        #pragma unroll
        for (int i = 0; i < 4; ++i)
            sh[rbase + q * 4 + i][t * 16 + cg] = f2bf(acc1[t][i]);
    copyout(sh, T2);
}

// score[e] = dot(T1[a0], T2[a1]) + bb
// 32 arcs/wave (two 16-arc groups), 4 lanes/arc; 16 independent 16B gathers
// in flight per lane. v8: __launch_bounds__(256,4) caps VGPR at 128 ->
// 4 waves/SIMD (16 waves/CU) resident, +33% in-flight gather bytes vs the
// 3-wave default (arc is L3-latency-bound: 256MB random gather over a
// 25.6MB L3-resident table).
__global__ __launch_bounds__(256, 4) void arc_kernel(
    const int* __restrict__ arcs,
    const unsigned short* __restrict__ T1,
    const unsigned short* __restrict__ T2,
    const float* __restrict__ bil_b,
    float* __restrict__ out, int E)
{
    const int tid  = threadIdx.x;
    const int lane = tid & 63;
    long long gw = ((long long)blockIdx.x * 256 + tid) >> 6;   // global wave id
    long long e0 = gw * 32;        // 32 arcs per wave
    int aidx = lane >> 2;          // arc-in-group (0..15)
    int s    = lane & 3;           // lane within arc

    // 64 distinct index ints per wave: arc k's (a0,a1) at lanes (2k, 2k+1)
    long long ii = e0 * 2 + lane;
    long long iimax = (long long)E * 2 - 1;
    int iv = arcs[ii <= iimax ? ii : iimax];
    int a0A = __shfl(iv, aidx * 2, 64);
    int a1A = __shfl(iv, aidx * 2 + 1, 64);
    int a0B = __shfl(iv, 32 + aidx * 2, 64);
    int a1B = __shfl(iv, 32 + aidx * 2 + 1, 64);

    const int4* PA = (const int4*)(T1 + (size_t)a0A * D);
    const int4* QA = (const int4*)(T2 + (size_t)a1A * D);
    const int4* PB = (const int4*)(T1 + (size_t)a0B * D);
    const int4* QB = (const int4*)(T2 + (size_t)a1B * D);

    // issue all 16 gathers up front
    int4 xA0 = PA[s];      int4 xA1 = PA[s + 4];
    int4 xA2 = PA[s + 8];  int4 xA3 = PA[s + 12];
    int4 yA0 = QA[s];      int4 yA1 = QA[s + 4];
    int4 yA2 = QA[s + 8];  int4 yA3 = QA[s + 12];
    int4 xB0 = PB[s];      int4 xB1 = PB[s + 4];
    int4 xB2 = PB[s + 8];  int4 xB3 = PB[s + 12];
    int4 yB0 = QB[s];      int4 yB1 = QB[s + 4];
    int4 yB2 = QB[s + 8];  int4 yB3 = QB[s + 12];

    auto dot16 = [](int4 x0, int4 x1, int4 x2, int4 x3,
                    int4 y0, int4 y1, int4 y2, int4 y3) -> float {
        float acc = 0.0f;
        acc += bflo(x0.x)*bflo(y0.x) + bfhi(x0.x)*bfhi(y0.x);
        acc += bflo(x0.y)*bflo(y0.y) + bfhi(x0.y)*bfhi(y0.y);
        acc += bflo(x0.z)*bflo(y0.z) + bfhi(x0.z)*bfhi(y0.z);
        acc += bflo(x0.w)*bflo(y0.w) + bfhi(x0.w)*bfhi(y0.w);
        acc += bflo(x1.x)*bflo(y1.x) + bfhi(x1.x)*bfhi(y1.x);
        acc += bflo(x1.y)*bflo(y1.y) + bfhi(x1.y)*bfhi(y1.y);
        acc += bflo(x1.z)*bflo(y1.z) + bfhi(x1.z)*bfhi(y1.z);
        acc += bflo(x1.w)*bflo(y1.w) + bfhi(x1.w)*bfhi(y1.w);
        acc += bflo(x2.x)*bflo(y2.x) + bfhi(x2.x)*bfhi(y2.x);
        acc += bflo(x2.y)*bflo(y2.y) + bfhi(x2.y)*bfhi(y2.y);
        acc += bflo(x2.z)*bflo(y2.z) + bfhi(x2.z)*bfhi(y2.z);
        acc += bflo(x2.w)*bflo(y2.w) + bfhi(x2.w)*bfhi(y2.w);
        acc += bflo(x3.x)*bflo(y3.x) + bfhi(x3.x)*bfhi(y3.x);
        acc += bflo(x3.y)*bflo(y3.y) + bfhi(x3.y)*bfhi(y3.y);
        acc += bflo(x3.z)*bflo(y3.z) + bfhi(x3.z)*bfhi(y3.z);
        acc += bflo(x3.w)*bflo(y3.w) + bfhi(x3.w)*bfhi(y3.w);
        return acc;
    };

    float accA = dot16(xA0, xA1, xA2, xA3, yA0, yA1, yA2, yA3);
    float accB = dot16(xB0, xB1, xB2, xB3, yB0, yB1, yB2, yB3);

    accA += __shfl_xor(accA, 1, 64);
    accA += __shfl_xor(accA, 2, 64);
    accB += __shfl_xor(accB, 1, 64);
    accB += __shfl_xor(accB, 2, 64);

    if (s == 0) {
        float bb = bil_b[0];
        long long eA = e0 + aidx;
        long long eB = e0 + 16 + aidx;
        if (eA < E) out[eA] = accA + bb;
        if (eB < E) out[eB] = accB + bb;
    }
}

extern "C" void kernel_launch(void* const* d_in, const int* in_sizes, int n_in,
                              void* d_out, int out_size, void* d_ws, size_t ws_size,
                              hipStream_t stream) {
    const float* z      = (const float*)d_in[0];
    const int*   arcs   = (const int*)d_in[1];
    const float* lin1_w = (const float*)d_in[2];
    const float* lin1_b = (const float*)d_in[3];
    const float* lin2_w = (const float*)d_in[4];
    const float* lin2_b = (const float*)d_in[5];
    const float* bil_w  = (const float*)d_in[6];
    const float* bil_b  = (const float*)d_in[7];
    const float* norm_w = (const float*)d_in[8];
    const float* norm_b = (const float*)d_in[9];
    float* out = (float*)d_out;

    const int N = in_sizes[0] / D;
    const int E = in_sizes[1] / 2;

    unsigned short* wfrag = (unsigned short*)d_ws;          // 3 * 16384 shorts
    unsigned short* T1 = wfrag + 3 * 16384;
    unsigned short* T2 = T1 + (size_t)N * D;

    wconv<<<24, 256, 0, stream>>>(lin1_w, lin2_w, bil_w, wfrag);

    node_kernel<<<(N + TM - 1) / TM, 256, 0, stream>>>(
        z, wfrag, lin1_b, lin2_b, norm_w, norm_b, T1, T2, N);

    long long waves = ((long long)E + 31) / 32;
    int blocks = (int)((waves + 3) / 4);
    arc_kernel<<<blocks, 256, 0, stream>>>(arcs, T1, T2, bil_b, out, E);
}